// Round 13
// baseline (162.734 us; speedup 1.0000x reference)
//
#include <hip/hip_runtime.h>
#include <hip/hip_bf16.h>
#include <math.h>

#define B_ROWS 4096
#define D_DIM 512
#define TWO_B 8192
#define HW_N 256
#define BASE_T 0.07f
#define ALPHA_C 0.5f
#define LOG2E 1.44269504088896340736f

typedef float v4f __attribute__((ext_vector_type(4)));

__device__ __forceinline__ float fast_exp2(float x) {
#if __has_builtin(__builtin_amdgcn_exp2f)
    return __builtin_amdgcn_exp2f(x);
#else
    return exp2f(x);
#endif
}

// ---------------------------------------------------------------------------
// Kernel 1: normalize, temps, pos_sim; write X as packed fp8 e4m3 (OCP).
// ---------------------------------------------------------------------------
__global__ __launch_bounds__(256) void prep_kernel(
    const float* __restrict__ emb1, const float* __restrict__ emb2,
    const float* __restrict__ att, unsigned short* __restrict__ X8,
    float* __restrict__ inv_temp, float* __restrict__ pos)
{
    const int b = blockIdx.x;
    const int t = threadIdx.x;
    const float2 a1 = ((const float2*)(emb1 + (size_t)b * D_DIM))[t];
    const float2 a2 = ((const float2*)(emb2 + (size_t)b * D_DIM))[t];
    float av = att[(size_t)b * HW_N + t];
    float s1  = a1.x * a1.x + a1.y * a1.y;
    float s2  = a2.x * a2.x + a2.y * a2.y;
    float s12 = a1.x * a2.x + a1.y * a2.y;
    #pragma unroll
    for (int m = 1; m < 64; m <<= 1) {
        s1  += __shfl_xor(s1, m, 64);
        s2  += __shfl_xor(s2, m, 64);
        s12 += __shfl_xor(s12, m, 64);
        av  += __shfl_xor(av, m, 64);
    }
    __shared__ float red[4][4];
    const int w = t >> 6, lane = t & 63;
    if (lane == 0) { red[w][0] = s1; red[w][1] = s2; red[w][2] = s12; red[w][3] = av; }
    __syncthreads();
    const float T1  = red[0][0] + red[1][0] + red[2][0] + red[3][0];
    const float T2  = red[0][1] + red[1][1] + red[2][1] + red[3][1];
    const float T12 = red[0][2] + red[1][2] + red[2][2] + red[3][2];
    const float Ta  = red[0][3] + red[1][3] + red[2][3] + red[3][3];
    const float i1 = 1.0f / fmaxf(sqrtf(T1), 1e-12f);
    const float i2 = 1.0f / fmaxf(sqrtf(T2), 1e-12f);
    const float it = 1.0f / (BASE_T * (1.0f + ALPHA_C * (Ta * (1.0f / 256.0f))));
    const int p1 = __builtin_amdgcn_cvt_pk_fp8_f32(a1.x * i1, a1.y * i1, 0, false);
    const int p2 = __builtin_amdgcn_cvt_pk_fp8_f32(a2.x * i2, a2.y * i2, 0, false);
    X8[(size_t)b * 256 + t]            = (unsigned short)(p1 & 0xffff);
    X8[(size_t)(b + B_ROWS) * 256 + t] = (unsigned short)(p2 & 0xffff);
    if (t == 0) {
        inv_temp[b] = it * LOG2E;
        inv_temp[b + B_ROWS] = it * LOG2E;
        pos[b] = (T12 * i1 * i2) * it;       // ln units, exact fp32
    }
}

// ---------------------------------------------------------------------------
// Kernel 2: triangular Gram (rb<=cb), FP8 e4m3. ONE staging phase:
// all 128 KB (A,B full K=512) staged in a single glds burst -> single
// exposed fill, zero drains during compute. 512 threads = 8 waves
// (2/SIMD — R9 lesson). K-split: waves 0-3 compute over K[0,256),
// waves 4-7 over K[256,512); accs merged via LDS (staging buffer reused
// after an empty-queue barrier). R8's swizzle/epilogue/partial scheme.
// LDS layout: A0[0,32K) Ah1[32K,64K) B0[64K,96K) B1[96K,128K).
// ---------------------------------------------------------------------------
__device__ __forceinline__ void gload_lds16(const void* g, void* s) {
    __builtin_amdgcn_global_load_lds(
        (const __attribute__((address_space(1))) unsigned int*)g,
        (__attribute__((address_space(3))) unsigned int*)s,
        16, 0, 0);
}

__global__ __launch_bounds__(512, 1) void gram_kernel(
    const unsigned char* __restrict__ X8,
    const float* __restrict__ inv_temp,
    float* __restrict__ partial)
{
    extern __shared__ unsigned char sm[];

    // --- XCD-contiguous remap: 2080 = 8 XCDs x 260 contiguous tri-ids ---
    const int bid = (blockIdx.x & 7) * 260 + (blockIdx.x >> 3);
    int rb = (int)((129.0f - sqrtf(129.0f * 129.0f - 8.0f * (float)bid)) * 0.5f);
    rb = rb < 0 ? 0 : (rb > 63 ? 63 : rb);
    while (rb > 0 && (rb * (129 - rb)) / 2 > bid) rb--;
    while (rb < 63 && ((rb + 1) * (129 - (rb + 1))) / 2 <= bid) rb++;
    const int cb = rb + (bid - (rb * (129 - rb)) / 2);

    const int rowBase = rb * 128;
    const int colBase = cb * 128;

    const int tid  = threadIdx.x;
    const int w    = tid >> 6;      // 0..7
    const int kg   = w >> 2;        // K-half group 0/1
    const int ws   = w & 3;         // wave-in-group
    const int lane = tid & 63;
    const int quad = lane >> 4;
    const int t    = lane & 15;
    const int wm   = ws >> 1;
    const int wn   = ws & 1;

    // staging roles: each glds = 4 rows x 16 units(16B) = 1 KB
    const int srow   = lane >> 4;   // 0..3
    const int schunk = lane & 15;   // 0..15

    const unsigned char* Arow0 = X8 + (size_t)rowBase * D_DIM;
    const unsigned char* Brow0 = X8 + (size_t)colBase * D_DIM;

    v4f acc[4][4];
    #pragma unroll
    for (int a = 0; a < 4; a++)
        #pragma unroll
        for (int b2 = 0; b2 < 4; b2++)
            acc[a][b2] = v4f{0.0f, 0.0f, 0.0f, 0.0f};

    // ---- single staging burst: 128 glds groups, wave w takes 16 ----
    #pragma unroll
    for (int j = 0; j < 16; j++) {
        const int g2  = w * 16 + j;        // 0..127, wave-uniform
        const int buf = g2 >> 5;           // 0:A0 1:A1 2:B0 3:B1
        const int rg  = g2 & 31;           // 4-row group
        const int r   = rg * 4 + srow;
        const int gc  = schunk ^ (r & 15); // XOR swizzle via global unit
        const unsigned char* base = (buf & 2) ? Brow0 : Arow0;
        const int khalf = (buf & 1) * 256;
        gload_lds16(base + (size_t)r * D_DIM + khalf + gc * 16,
                    &sm[buf * 32768 + rg * 1024]);
    }
    __syncthreads();    // the ONE exposed fill drain

    // ---- compute: each wave 64x64 over its K-half (8 k-steps) ----
    const unsigned char* bA = sm + kg * 32768;
    const unsigned char* bB = sm + 65536 + kg * 32768;
    #pragma unroll
    for (int s = 0; s < 8; s++) {
        const int pu = (s * 2 + (quad >> 1)) ^ t;   // LDS unit (swizzled)
        const int off = pu * 16 + (quad & 1) * 8;
        long aF[4], bF[4];
        #pragma unroll
        for (int mi = 0; mi < 4; mi++)
            aF[mi] = *(const long*)&bA[(wm * 64 + mi * 16 + t) * 256 + off];
        #pragma unroll
        for (int ni = 0; ni < 4; ni++)
            bF[ni] = *(const long*)&bB[(wn * 64 + ni * 16 + t) * 256 + off];
        #pragma unroll
        for (int mi = 0; mi < 4; mi++)
            #pragma unroll
            for (int ni = 0; ni < 4; ni++)
                acc[mi][ni] = __builtin_amdgcn_mfma_f32_16x16x32_fp8_fp8(
                    aF[mi], bF[ni], acc[mi][ni], 0, 0, 0);
    }

    // ---- merge K-halves through LDS (no vmem pending: cheap barriers) ----
    __syncthreads();
    if (kg == 1) {
        #pragma unroll
        for (int mi = 0; mi < 4; mi++)
            #pragma unroll
            for (int ni = 0; ni < 4; ni++)
                *(v4f*)&sm[ws * 16384 + (((mi * 4 + ni) * 64) + lane) * 16] =
                    acc[mi][ni];
    }
    __syncthreads();
    if (kg == 1) return;    // no barriers remain; kg0 waves finish alone

    #pragma unroll
    for (int mi = 0; mi < 4; mi++)
        #pragma unroll
        for (int ni = 0; ni < 4; ni++) {
            const v4f o = *(const v4f*)
                &sm[ws * 16384 + (((mi * 4 + ni) * 64) + lane) * 16];
            acc[mi][ni] = acc[mi][ni] + o;
        }

    // ---- Epilogue 1: row sums (temp_i), slice 2*cb+wn ----
    v4f itv[4];
    #pragma unroll
    for (int mi = 0; mi < 4; mi++)
        itv[mi] = *(const v4f*)&inv_temp[rowBase + wm * 64 + mi * 16 + quad * 4];

    float* prow = partial + (size_t)(cb * 2 + wn) * TWO_B;
    #pragma unroll
    for (int mi = 0; mi < 4; mi++) {
        #pragma unroll
        for (int r = 0; r < 4; r++) {
            const int i = rowBase + wm * 64 + mi * 16 + quad * 4 + r;
            const float it = itv[mi][r];
            float s = 0.0f;
            #pragma unroll
            for (int ni = 0; ni < 4; ni++) {
                const int j = colBase + wn * 64 + ni * 16 + t;
                const float v = fast_exp2(acc[mi][ni][r] * it);
                s += (i == j) ? 0.0f : v;
            }
            s += __shfl_xor(s, 1, 64);
            s += __shfl_xor(s, 2, 64);
            s += __shfl_xor(s, 4, 64);
            s += __shfl_xor(s, 8, 64);
            if (t == 0) prow[i] = s;
        }
    }

    // ---- Epilogue 2 (off-diag): col sums (temp_j), slice 2*rb+wm ----
    if (rb != cb) {
        float itj[4];
        float cs[4] = {0.0f, 0.0f, 0.0f, 0.0f};
        #pragma unroll
        for (int ni = 0; ni < 4; ni++)
            itj[ni] = inv_temp[colBase + wn * 64 + ni * 16 + t];
        #pragma unroll
        for (int mi = 0; mi < 4; mi++)
            #pragma unroll
            for (int r = 0; r < 4; r++)
                #pragma unroll
                for (int ni = 0; ni < 4; ni++)
                    cs[ni] += fast_exp2(acc[mi][ni][r] * itj[ni]);
        float* pcol = partial + (size_t)(rb * 2 + wm) * TWO_B;
        #pragma unroll
        for (int ni = 0; ni < 4; ni++) {
            cs[ni] += __shfl_xor(cs[ni], 16, 64);
            cs[ni] += __shfl_xor(cs[ni], 32, 64);
            if (quad == 0) pcol[colBase + wn * 64 + ni * 16 + t] = cs[ni];
        }
    }
}

// ---------------------------------------------------------------------------
// Kernel 3a: denom = sum of 128 slices (128 blocks x 64 thr for BW spread)
// ---------------------------------------------------------------------------
__global__ __launch_bounds__(64) void finish1(
    const float* __restrict__ partial, const float* __restrict__ pos,
    float* __restrict__ blockSums)
{
    const int i = blockIdx.x * 64 + threadIdx.x;
    float d = 0.0f;
    #pragma unroll 8
    for (int s = 0; s < 128; s++) d += partial[(size_t)s * TWO_B + i];
    float li = logf(d) - pos[i & (B_ROWS - 1)];
    #pragma unroll
    for (int m = 1; m < 64; m <<= 1) li += __shfl_xor(li, m, 64);
    if (threadIdx.x == 0) blockSums[blockIdx.x] = li;
}

__global__ void finish2(const float* __restrict__ blockSums, float* __restrict__ out)
{
    const int lane = threadIdx.x;
    float v = blockSums[lane] + blockSums[lane + 64];
    #pragma unroll
    for (int m = 1; m < 64; m <<= 1) v += __shfl_xor(v, m, 64);
    if (lane == 0) out[0] = v * (1.0f / 8192.0f);
}

// ---------------------------------------------------------------------------
extern "C" void kernel_launch(void* const* d_in, const int* in_sizes, int n_in,
                              void* d_out, int out_size, void* d_ws, size_t ws_size,
                              hipStream_t stream) {
    const float* emb1 = (const float*)d_in[0];
    const float* emb2 = (const float*)d_in[1];
    const float* att  = (const float*)d_in[2];
    float* out = (float*)d_out;

    char* ws = (char*)d_ws;
    // X8 fp8 [8192*512]        @ 0        (4 MB)
    // inv_temp f32 [8192]      @ 4194304
    // pos f32 [4096]           @ 4227072
    // partial f32 [128*8192]   @ 4243456  (4 MB)
    // blockSums f32 [128]      @ 8437760
    unsigned short* X8 = (unsigned short*)ws;
    float* inv_temp    = (float*)(ws + 4194304);
    float* pos         = (float*)(ws + 4227072);
    float* partial     = (float*)(ws + 4243456);
    float* blockSums   = (float*)(ws + 8437760);

    static bool attr_set = false;  // host-side only; same device work every call
    if (!attr_set) {
        hipFuncSetAttribute((const void*)gram_kernel,
                            hipFuncAttributeMaxDynamicSharedMemorySize, 131072);
        attr_set = true;
    }

    prep_kernel<<<B_ROWS, 256, 0, stream>>>(emb1, emb2, att, X8, inv_temp, pos);
    gram_kernel<<<2080, 512, 131072, stream>>>((const unsigned char*)X8,
                                               inv_temp, partial);
    finish1<<<TWO_B / 64, 64, 0, stream>>>(partial, pos, blockSums);
    finish2<<<1, 64, 0, stream>>>(blockSums, out);
}